// Round 4
// baseline (406.828 us; speedup 1.0000x reference)
//
#include <hip/hip_runtime.h>
#include <hip/hip_bf16.h>
#include <math.h>

// ---------- types ----------
typedef __attribute__((ext_vector_type(8))) short s8vec;     // 8 x bf16 bits (4 VGPRs)
typedef __attribute__((ext_vector_type(16))) float f32x16;   // 32x32 MFMA C/D
typedef __attribute__((ext_vector_type(4))) unsigned short us4;

__device__ __forceinline__ unsigned short f2bf(float f) {
  unsigned u = __float_as_uint(f);
  u = (u + 0x7fffu + ((u >> 16) & 1u)) >> 16;   // RNE
  return (unsigned short)u;
}
__device__ __forceinline__ float bf2f(unsigned short u) {
  return __uint_as_float(((unsigned)u) << 16);
}

// fast gelu: t * sigmoid(1.5957691t + 0.07135481t^3); |err vs erf-gelu| < 3e-3
__device__ __forceinline__ float fast_gelu(float t) {
  float t2 = t * t;
  float u = t * (1.59576912f + 0.07135481f * t2);
  float e = __expf(-u);
  return t * __frcp_rn(1.0f + e);
}

// async global->LDS, 16B per lane. LDS dest = wave-uniform base + lane*16.
__device__ __forceinline__ void async_ld16(const unsigned short* g, unsigned short* l) {
  __builtin_amdgcn_global_load_lds(
      (__attribute__((address_space(1))) void*)g,
      (__attribute__((address_space(3))) void*)l, 16, 0, 0);
}

// ============================================================================
// 256xBN NT GEMM: C[M,N] = A[M,K] * Bt[N,K]^T              (BN = 256 or 128)
//
// Round-3 A/B isolated: the 2-window "batch ALL ds_reads + deep read-ahead +
// counted lgkm" shape (BN=128 path) WON; the 4-window read-ahead LOST.  This
// round unifies both BN on the winning shape and prunes barriers to the
// provable minimum: 2 per K-tile.
//
// Per K-tile (2 windows; 8 waves; 32x32x16 bf16; double-buffered LDS):
//  WA: read B(4*NF)+q0+q1 (=12/16), then READ-AHEAD q2,q3 (8);
//      stage A23(t+1, other buf);
//      lgkm(8)  [q2,q3 still in flight; DS retires in-order]
//      setprio1; MFMA half1 (q0,q1: 8*NF) ; setprio0 ; s_barrier
//  WB: stage B0..NB-1(t+2) + A01(t+2) (this buf);
//      lgkm(0); setprio1; MFMA half2 (q2,q3) ; setprio0;
//      vmcnt(NB+2) (tail: 0) ; s_barrier
//
// Hazard ledger (re-derived for 2 barriers):
//  - WB stages overwrite B/A01 read in WA: all waves pass lgkm(8) (B,q0,q1
//    complete) before the WA-end barrier; q2,q3 reads target A23 (disjoint).
//  - t+1.WA stages A23(t+2) into this buf: this tile's q2,q3 reads complete
//    at WB's lgkm(0), before the boundary barrier.
//  - t.WA stages A23(t+1) into other buf: that region's readers (t-1's q2,q3)
//    completed before t-1's boundary barrier.
//  - Boundary vmcnt: queue = [t-1.WB: NB+2 (t+1), t.WA: 2 (t+1), t.WB: NB+2
//    (t+2)]; draining the oldest NB+4 completes tile t+1 -> vmcnt(NB+2).
//
// T1 XCD-aware bijective remap (nwg%8==0, gx/gy pow2 at all sites).
// LDS swizzle (0 measured conflict cycles): 16B chunk c of row r at
// c ^ (r&7) ^ ((r>>3)&3); global source pre-swizzled, LDS linear.  The
// swizzle chunk is stripe-invariant ((r>>3)&3 == sub for all A-stripes q,
// == w&3 for all B-stripes j), so stripe pointers collapse to one base +
// uniform offset (q*32*K / j*64*K) — frees ~12 VGPR for the read-ahead regs.
// C/D: col=lane&31, row=(reg&3)+8*(reg>>2)+4*(lane>>5).
// EPI: 0 = out_bf16 = acc*scale; 1 = out_f32 = acc+res;
//      2 = out_bf16 = gelu(acc+bias); 3 = out_f32 = acc+bias+res
// ============================================================================

#define STA(q, tk, bofs)                                                    \
  async_ld16(srcA0 + (size_t)(q) * 32 * K + ((size_t)(tk) << 6),            \
             &As[(bofs) + ldsA0 + (q) * 2048])
#define STB(j, tk, bofs)                                                    \
  async_ld16(srcB0 + (size_t)(j) * 64 * K + ((size_t)(tk) << 6),            \
             &Bs[(bofs) + ldsB0 + (j) * 4096])

#define SB0() __builtin_amdgcn_sched_barrier(0)

template <int BN, int EPI>
__global__ __launch_bounds__(512, 2) void gemm_nt8(
    const unsigned short* __restrict__ A, const unsigned short* __restrict__ B,
    float* __restrict__ outF, unsigned short* __restrict__ outB,
    const float* __restrict__ bias, const float* __restrict__ res,
    int M, int N, int K,
    long long bA, long long bB, long long bO, long long bR, float scale)
{
  static_assert(BN == 256 || BN == 128, "BN must be 256 or 128");
  constexpr int NB = BN / 64;      // B stage stripes per K-tile (4 or 2)
  constexpr int NF = BN / 128;     // N-frags per wave (2 or 1)
  constexpr int WN = BN / 4;       // wave N extent (64 or 32)
  constexpr int ABUF = 256 * 64;   // elements per A buffer (32 KiB)
  constexpr int BBUF = BN * 64;

  __shared__ __align__(16) unsigned short As[2 * ABUF];
  __shared__ __align__(16) unsigned short Bs[2 * BBUF];

  (void)M;
  const int tid = threadIdx.x;
  const int w = tid >> 6;          // wave 0..7
  const int l = tid & 63;

  // ---- T1: XCD-aware bijective remap (nwg % 8 == 0, gx/gy pow2) ----
  const unsigned gx = gridDim.x, gy = gridDim.y;
  unsigned lin = blockIdx.x + gx * (blockIdx.y + gy * blockIdx.z);
  const unsigned nwg = gx * gy * gridDim.z;
  lin = (lin & 7u) * (nwg >> 3) + (lin >> 3);
  const unsigned bx = lin & (gx - 1u);
  const unsigned tmp = lin >> __builtin_ctz(gx);
  const unsigned by = tmp & (gy - 1u);
  const unsigned bz = tmp >> __builtin_ctz(gy);

  const int z = (int)bz;
  A += (size_t)z * bA;
  B += (size_t)z * bB;
  const size_t tileM = (size_t)by * 256;
  const size_t tileN = (size_t)bx * BN;

  // ---- staging bases (global pre-swizzled, LDS linear) ----
  const int sub = w & 3, half = w >> 2;
  const int rA = sub * 8 + half * 128 + (l >> 3);          // stripe q adds q*32
  const int cA = (l & 7) ^ (rA & 7) ^ ((rA >> 3) & 3);     // invariant in q
  const unsigned short* srcA0 = A + (tileM + rA) * (size_t)K + (cA << 3);
  const int ldsA0 = (sub * 8 + half * 128) * 64;

  const int rB = w * 8 + (l >> 3);                         // stripe j adds j*64
  const int cB = (l & 7) ^ (rB & 7) ^ ((rB >> 3) & 3);     // invariant in j
  const unsigned short* srcB0 = B + (tileN + rB) * (size_t)K + (cB << 3);
  const int ldsB0 = (w * 8) * 64;

  // ---- compute-side fragment addressing ----
  const int wm = half;             // wave M origin / 128
  const int wn = sub;              // wave N origin / WN
  const int fr = l & 31;
  const int fq = l >> 5;
  const int swz = (l & 7) ^ ((l >> 3) & 3);            // = f(row) for row=base+fr, base%32==0
  int pc[4];
#pragma unroll
  for (int s = 0; s < 4; ++s) pc[s] = ((((s << 1) + fq) ^ swz) << 3);
  const int aoff = (wm * 128 + fr) * 64;
  int boff[NF];
#pragma unroll
  for (int nf = 0; nf < NF; ++nf) boff[nf] = (wn * WN + nf * 32 + fr) * 64;

  f32x16 acc[4][NF] = {};
  const int NT = K >> 6;           // K-tiles (>=16 and even at all call sites)

  // ---- prologue: t0 full (oldest 4+NB), then t1 B (NB) + A01 (2) ----
  STA(0, 0, 0); STA(1, 0, 0); STA(2, 0, 0); STA(3, 0, 0);
#pragma unroll
  for (int j = 0; j < NB; ++j) STB(j, 0, 0);
#pragma unroll
  for (int j = 0; j < NB; ++j) STB(j, 1, BBUF);
  STA(0, 1, ABUF); STA(1, 1, ABUF);
  if constexpr (NB == 4) asm volatile("s_waitcnt vmcnt(6)" ::: "memory");
  else                   asm volatile("s_waitcnt vmcnt(4)" ::: "memory");
  __builtin_amdgcn_s_barrier();

  auto tile = [&](int t, int bf) {
    const int aB = bf * ABUF, bBo = bf * BBUF, oaB = (bf ^ 1) * ABUF;
    const bool g1 = (t + 1 < NT), g2 = (t + 2 < NT);
    s8vec b[NF][4], aA[2][4], aC[2][4];

    // -- WA: read B,q0,q1; read-ahead q2,q3; stage A23(t+1, other buf) --
#pragma unroll
    for (int s = 0; s < 4; ++s) {
#pragma unroll
      for (int nf = 0; nf < NF; ++nf)
        b[nf][s] = *(const s8vec*)&Bs[bBo + boff[nf] + pc[s]];
      aA[0][s] = *(const s8vec*)&As[aB + aoff + 0 * 2048 + pc[s]];
      aA[1][s] = *(const s8vec*)&As[aB + aoff + 1 * 2048 + pc[s]];
    }
    SB0();                         // pin batch boundary: (B,q0,q1) | (q2,q3)
#pragma unroll
    for (int s = 0; s < 4; ++s) {
      aC[0][s] = *(const s8vec*)&As[aB + aoff + 2 * 2048 + pc[s]];
      aC[1][s] = *(const s8vec*)&As[aB + aoff + 3 * 2048 + pc[s]];
    }
    if (g1) { STA(2, t + 1, oaB); STA(3, t + 1, oaB); }
    SB0();
    asm volatile("s_waitcnt lgkmcnt(8)" ::: "memory");   // B,q0,q1 done; q2,q3 in flight
    SB0();
    __builtin_amdgcn_s_setprio(1);
#pragma unroll
    for (int s = 0; s < 4; ++s)
#pragma unroll
      for (int i = 0; i < 2; ++i)
#pragma unroll
        for (int nf = 0; nf < NF; ++nf)
          acc[i][nf] = __builtin_amdgcn_mfma_f32_32x32x16_bf16(aA[i][s], b[nf][s], acc[i][nf], 0, 0, 0);
    SB0();
    __builtin_amdgcn_s_setprio(0);
    __builtin_amdgcn_s_barrier();   // all waves past lgkm(8) -> B/A01 regions safe to restage

    // -- WB: stage B(t+2)+A01(t+2) (this buf); MFMA half2; boundary vmcnt --
    if (g2) {
#pragma unroll
      for (int j = 0; j < NB; ++j) STB(j, t + 2, bBo);
      STA(0, t + 2, aB); STA(1, t + 2, aB);
    }
    SB0();
    asm volatile("s_waitcnt lgkmcnt(0)" ::: "memory");   // q2,q3 done
    SB0();
    __builtin_amdgcn_s_setprio(1);
#pragma unroll
    for (int s = 0; s < 4; ++s)
#pragma unroll
      for (int i = 0; i < 2; ++i)
#pragma unroll
        for (int nf = 0; nf < NF; ++nf)
          acc[2 + i][nf] = __builtin_amdgcn_mfma_f32_32x32x16_bf16(aC[i][s], b[nf][s], acc[2 + i][nf], 0, 0, 0);
    SB0();
    __builtin_amdgcn_s_setprio(0);
    if (g2) {
      if constexpr (NB == 4) asm volatile("s_waitcnt vmcnt(6)" ::: "memory");
      else                   asm volatile("s_waitcnt vmcnt(4)" ::: "memory");
    } else {
      asm volatile("s_waitcnt vmcnt(0)" ::: "memory");
    }
    __builtin_amdgcn_s_barrier();   // tile t+1 fully resident
  };

  for (int t = 0; t < NT; t += 2) { tile(t, 0); tile(t + 1, 1); }

  // ---- epilogue.  C/D: col = lane&31, row = (reg&3)+8*(reg>>2)+4*(lane>>5) ----
  float* oF = outF + (size_t)z * bO;
  unsigned short* oB = outB + (size_t)z * bO;
  const float* rs = res + (size_t)z * bR;

  float bcol[NF];
  if (EPI >= 2) {
#pragma unroll
    for (int nf = 0; nf < NF; ++nf) bcol[nf] = bias[tileN + wn * WN + nf * 32 + fr];
  }

#pragma unroll
  for (int mf = 0; mf < 4; ++mf) {
#pragma unroll
    for (int r = 0; r < 16; ++r) {
      const size_t row = tileM + wm * 128 + (mf << 5) + (r & 3) + ((r >> 2) << 3) + (fq << 2);
      const size_t rb = row * (size_t)N;
#pragma unroll
      for (int nf = 0; nf < NF; ++nf) {
        const size_t col = tileN + wn * WN + (nf << 5) + fr;
        const float v = acc[mf][nf][r];
        if (EPI == 0) {
          oB[rb + col] = f2bf(v * scale);
        } else if (EPI == 1) {
          oF[rb + col] = v + rs[rb + col];
        } else if (EPI == 2) {
          oB[rb + col] = f2bf(fast_gelu(v + bcol[nf]));
        } else {
          oF[rb + col] = v + bcol[nf] + rs[rb + col];
        }
      }
    }
  }
}

// ---------- LayerNorm over rows of 1024 fp32 -> bf16 ----------
__global__ __launch_bounds__(256) void ln_row(
    const float* __restrict__ x, const float* __restrict__ gamma,
    const float* __restrict__ beta, unsigned short* __restrict__ out)
{
  const int row = blockIdx.x;
  const float4* xr = (const float4*)(x + (size_t)row * 1024);
  const int tid = threadIdx.x;
  float4 v = xr[tid];
  float s = v.x + v.y + v.z + v.w;
  float q = v.x * v.x + v.y * v.y + v.z * v.z + v.w * v.w;
#pragma unroll
  for (int off = 32; off > 0; off >>= 1) {
    s += __shfl_down(s, off);
    q += __shfl_down(q, off);
  }
  __shared__ float rs_[4], rq_[4];
  const int w = tid >> 6, l = tid & 63;
  if (l == 0) { rs_[w] = s; rq_[w] = q; }
  __syncthreads();
  s = rs_[0] + rs_[1] + rs_[2] + rs_[3];
  q = rq_[0] + rq_[1] + rq_[2] + rq_[3];
  const float mu = s * (1.0f / 1024.0f);
  const float var = q * (1.0f / 1024.0f) - mu * mu;
  const float rstd = rsqrtf(var + 1e-5f);
  const float4 g = ((const float4*)gamma)[tid];
  const float4 b = ((const float4*)beta)[tid];
  us4 o;
  o.x = f2bf((v.x - mu) * rstd * g.x + b.x);
  o.y = f2bf((v.y - mu) * rstd * g.y + b.y);
  o.z = f2bf((v.z - mu) * rstd * g.z + b.z);
  o.w = f2bf((v.w - mu) * rstd * g.w + b.w);
  ((us4*)(out + (size_t)row * 1024))[tid] = o;
}

// ---------- softmax over rows of 2048 bf16 -> bf16 ----------
__global__ __launch_bounds__(256) void softmax_row(
    const unsigned short* __restrict__ sc, unsigned short* __restrict__ pr)
{
  const int row = blockIdx.x;
  const s8vec* s8 = (const s8vec*)(sc + (size_t)row * 2048);
  const int tid = threadIdx.x;
  s8vec a = s8[tid];                 // 8 bf16
  float x[8];
#pragma unroll
  for (int i = 0; i < 8; ++i) x[i] = bf2f((unsigned short)a[i]);
  float mx = x[0];
#pragma unroll
  for (int i = 1; i < 8; ++i) mx = fmaxf(mx, x[i]);
#pragma unroll
  for (int off = 32; off > 0; off >>= 1) mx = fmaxf(mx, __shfl_down(mx, off));
  __shared__ float red[4];
  const int w = tid >> 6, l = tid & 63;
  if (l == 0) red[w] = mx;
  __syncthreads();
  mx = fmaxf(fmaxf(red[0], red[1]), fmaxf(red[2], red[3]));
  __syncthreads();
  float e[8], s = 0.f;
#pragma unroll
  for (int i = 0; i < 8; ++i) { e[i] = __expf(x[i] - mx); s += e[i]; }
#pragma unroll
  for (int off = 32; off > 0; off >>= 1) s += __shfl_down(s, off);
  if (l == 0) red[w] = s;
  __syncthreads();
  s = red[0] + red[1] + red[2] + red[3];
  const float inv = 1.0f / s;
  s8vec o;
#pragma unroll
  for (int i = 0; i < 8; ++i) o[i] = (short)f2bf(e[i] * inv);
  ((s8vec*)(pr + (size_t)row * 2048))[tid] = o;
}

// ---------- transpose + convert to bf16: in[R,C] -> out[C,R] ----------
template <bool BF16IN>
__global__ __launch_bounds__(256) void transpose_conv(
    const void* __restrict__ in_, unsigned short* __restrict__ out,
    int R, int C, long long bIn, long long bOut)
{
  __shared__ float tile[32][33];
  const int z = blockIdx.z;
  const int tx = threadIdx.x, ty = threadIdx.y;   // block (32,8)
  const int c0 = blockIdx.x * 32, r0 = blockIdx.y * 32;
  if (BF16IN) {
    const unsigned short* in = (const unsigned short*)in_ + (size_t)z * bIn;
    for (int i = ty; i < 32; i += 8)
      tile[i][tx] = bf2f(in[(size_t)(r0 + i) * C + c0 + tx]);
  } else {
    const float* in = (const float*)in_ + (size_t)z * bIn;
    for (int i = ty; i < 32; i += 8)
      tile[i][tx] = in[(size_t)(r0 + i) * C + c0 + tx];
  }
  __syncthreads();
  unsigned short* o = out + (size_t)z * bOut;
  for (int i = ty; i < 32; i += 8)
    o[(size_t)(c0 + i) * R + r0 + tx] = f2bf(tile[tx][i]);
}

// ---------- launch ----------
extern "C" void kernel_launch(void* const* d_in, const int* in_sizes, int n_in,
                              void* d_out, int out_size, void* d_ws, size_t ws_size,
                              hipStream_t stream)
{
  (void)in_sizes; (void)n_in; (void)out_size; (void)ws_size;
  const float* src = (const float*)d_in[0];
  const float* g1  = (const float*)d_in[1];
  const float* be1 = (const float*)d_in[2];
  const float* g2  = (const float*)d_in[3];
  const float* be2 = (const float*)d_in[4];
  const float* w1  = (const float*)d_in[5];
  const float* b1  = (const float*)d_in[6];
  const float* w2  = (const float*)d_in[7];
  const float* b2  = (const float*)d_in[8];
  float* out = (float*)d_out;

  // workspace layout (bytes). Peak = 184,549,376.
  char* ws = (char*)d_ws;
  const size_t SZ_NORMX  = (size_t)8192 * 1024 * 2;     // 16 MiB
  const size_t SZ_SCORES = (size_t)4 * 2048 * 2048 * 4; // 64 MiB region (scores bf16 uses half; hbuf uses all)
  const size_t SZ_PROBS  = (size_t)4 * 2048 * 2048 * 2; // 32 MiB
  const size_t SZ_X      = (size_t)8192 * 1024 * 4;     // 32 MiB
  const size_t SZ_W1T    = (size_t)1024 * 4096 * 2;     // 8 MiB

  unsigned short* normx  = (unsigned short*)(ws);
  unsigned short* normxT = (unsigned short*)(ws + SZ_NORMX);
  unsigned short* scores = (unsigned short*)(ws + 2 * SZ_NORMX);
  unsigned short* probs  = (unsigned short*)(ws + 2 * SZ_NORMX + SZ_SCORES);
  float*          xbuf   = (float*)(ws + 2 * SZ_NORMX + SZ_SCORES + SZ_PROBS);
  unsigned short* w1t    = (unsigned short*)(ws + 2 * SZ_NORMX + SZ_SCORES + SZ_PROBS + SZ_X);
  unsigned short* w2t    = (unsigned short*)(ws + 2 * SZ_NORMX + SZ_SCORES + SZ_PROBS + SZ_X + SZ_W1T);
  unsigned short* normx2 = normx;                       // reuse (dead after attn)
  unsigned short* hbuf   = scores;                      // reuse (dead after softmax)

  const dim3 tb(32, 8);
  // weights fp32 -> bf16 transposed (every call; ws is re-poisoned)
  transpose_conv<false><<<dim3(128, 32, 1), tb, 0, stream>>>(w1, w1t, 1024, 4096, 0, 0);
  transpose_conv<false><<<dim3(32, 128, 1), tb, 0, stream>>>(w2, w2t, 4096, 1024, 0, 0);

  // LN1
  ln_row<<<8192, 256, 0, stream>>>(src, g1, be1, normx);
  // normx^T per batch (for PV as NT)
  transpose_conv<true><<<dim3(32, 64, 4), tb, 0, stream>>>(
      normx, normxT, 2048, 1024, (long long)2048 * 1024, (long long)1024 * 2048);

  // scores = bf16(normx . normx^T / 32)
  gemm_nt8<256, 0><<<dim3(8, 8, 4), 512, 0, stream>>>(
      normx, normx, nullptr, scores, nullptr, nullptr,
      2048, 2048, 1024,
      (long long)2048 * 1024, (long long)2048 * 1024, (long long)2048 * 2048, 0, 0.03125f);

  // softmax rows (bf16 in/out)
  softmax_row<<<8192, 256, 0, stream>>>(scores, probs);

  // x = probs . normx + src
  gemm_nt8<128, 1><<<dim3(8, 8, 4), 512, 0, stream>>>(
      probs, normxT, xbuf, nullptr, nullptr, src,
      2048, 1024, 2048,
      (long long)2048 * 2048, (long long)1024 * 2048, (long long)2048 * 1024,
      (long long)2048 * 1024, 1.0f);

  // LN2
  ln_row<<<8192, 256, 0, stream>>>(xbuf, g2, be2, normx2);

  // h = gelu(normx2 . w1 + b1)
  gemm_nt8<256, 2><<<dim3(16, 32, 1), 512, 0, stream>>>(
      normx2, w1t, nullptr, hbuf, b1, nullptr,
      8192, 4096, 1024, 0, 0, 0, 0, 1.0f);

  // out = h . w2 + b2 + x
  gemm_nt8<128, 3><<<dim3(8, 32, 1), 512, 0, stream>>>(
      hbuf, w2t, out, nullptr, b2, xbuf,
      8192, 1024, 4096, 0, 0, 0, 0, 1.0f);
}

// Round 5
// 390.716 us; speedup vs baseline: 1.0412x; 1.0412x over previous
//
#include <hip/hip_runtime.h>
#include <hip/hip_bf16.h>
#include <math.h>

// ---------- types ----------
typedef __attribute__((ext_vector_type(8))) short s8vec;     // 8 x bf16 bits (4 VGPRs)
typedef __attribute__((ext_vector_type(16))) float f32x16;   // 32x32 MFMA C/D
typedef __attribute__((ext_vector_type(4))) float f32x4;     // 16x16 MFMA C/D
typedef __attribute__((ext_vector_type(4))) unsigned short us4;
typedef __attribute__((ext_vector_type(8))) unsigned short us8;

__device__ __forceinline__ unsigned short f2bf(float f) {
  unsigned u = __float_as_uint(f);
  u = (u + 0x7fffu + ((u >> 16) & 1u)) >> 16;   // RNE
  return (unsigned short)u;
}
__device__ __forceinline__ float bf2f(unsigned short u) {
  return __uint_as_float(((unsigned)u) << 16);
}

// fast gelu: t * sigmoid(1.5957691t + 0.07135481t^3); |err vs erf-gelu| < 3e-3
__device__ __forceinline__ float fast_gelu(float t) {
  float t2 = t * t;
  float u = t * (1.59576912f + 0.07135481f * t2);
  float e = __expf(-u);
  return t * __frcp_rn(1.0f + e);
}

// async global->LDS, 16B per lane. LDS dest = wave-uniform base + lane*16.
__device__ __forceinline__ void async_ld16(const unsigned short* g, unsigned short* l) {
  __builtin_amdgcn_global_load_lds(
      (__attribute__((address_space(1))) void*)g,
      (__attribute__((address_space(3))) void*)l, 16, 0, 0);
}

// ============================================================================
// 256xBN NT GEMM: C[M,N] = A[M,K] * Bt[N,K]^T              (BN = 256 or 128)
//
// BN=256: faithful m201-style 4-phase K-tile with 16x16x32 MFMA (the verified
// 1563-TF structure; rounds 0-4 all used 32x32x16 and plateaued at ~730 TF).
// Per wave (2M x 4N grid, wave tile 128x64): acc = f32x4[8 mf][4 nf].
// Phase p (p=0..3): reads A-frags mf=2p,2p+1 (4 ds_read_b128; ph0 also all B:
// +8), issues 2 stage stripes, [ph0: lgkm(8)], barrier, lgkm(0), setprio(1),
// 16 MFMA, setprio(0), counted vmcnt, barrier.
// Stage order during tile t (1-tile lookahead, other buf) = consumption order
// of tile t+1:  ph0: B01(t+1) | ph1: B23(t+1) | ph2: A01(t+1) | ph3: A23(t+1)
// A stripe q = rows {32q..32q+32} u {128+32q..} (consumed exactly at phase q).
// vmcnt ledger (per-thread queue, derived from first-use positions):
//   prologue: stage B0..3(0),A0..3(0); vmcnt(3)  [ph0 needs B*4+A0 = first 5]
//   ph0-end: queue [A1..A3(t),B01(t+1)]+... -> need A1 -> vmcnt(4)
//   ph1-end: need A2 -> vmcnt(5);  ph2-end: need A3 -> vmcnt(6)
//   ph3-end: queue = 8 stripes of t+1; next ph0 needs first 5 -> vmcnt(3)
//   last tile (no stages): 2,1,0,0.
// Every staged region is >=3 barriers dead (B(other) read only at ph0 of the
// previous tile; A(other) stripe q read at its phase q of the previous tile).
//
// BN=128: round-4 2-window schedule kept byte-identical (measured best there).
//
// T1 XCD-aware bijective remap (nwg%8==0, gx/gy pow2 at all sites).
// LDS swizzle (0 measured conflict cycles): 16B chunk c of row r at
// c ^ (r&7) ^ ((r>>3)&3); global source pre-swizzled, LDS linear.
// 16x16x32 frags: A row=l&15, k=(l>>4)*8+e; C/D col=l&15, row=(l>>4)*4+reg.
// EPI: 0 = out_bf16 = acc*scale; 1 = out_f32 = acc+res;
//      2 = out_bf16 = gelu(acc+bias); 3 = out_f32 = acc+bias+res
// ============================================================================

#define STA(q, tk, bofs)                                                    \
  async_ld16(srcA0 + (size_t)(q) * 32 * K + ((size_t)(tk) << 6),            \
             &As[(bofs) + ldsA0 + (q) * 2048])
#define STB(j, tk, bofs)                                                    \
  async_ld16(srcB0 + (size_t)(j) * 64 * K + ((size_t)(tk) << 6),            \
             &Bs[(bofs) + ldsB0 + (j) * 4096])

#define SB0() __builtin_amdgcn_sched_barrier(0)

template <int BN, int EPI>
__global__ __launch_bounds__(512, 2) void gemm_nt8(
    const unsigned short* __restrict__ A, const unsigned short* __restrict__ B,
    float* __restrict__ outF, unsigned short* __restrict__ outB,
    const float* __restrict__ bias, const float* __restrict__ res,
    int M, int N, int K,
    long long bA, long long bB, long long bO, long long bR, float scale)
{
  static_assert(BN == 256 || BN == 128, "BN must be 256 or 128");
  constexpr int NB = BN / 64;      // B stage stripes per K-tile (4 or 2)
  constexpr int ABUF = 256 * 64;   // elements per A buffer (32 KiB)
  constexpr int BBUF = BN * 64;

  __shared__ __align__(16) unsigned short As[2 * ABUF];
  __shared__ __align__(16) unsigned short Bs[2 * BBUF];

  (void)M;
  const int tid = threadIdx.x;
  const int w = tid >> 6;          // wave 0..7
  const int l = tid & 63;

  // ---- T1: XCD-aware bijective remap (nwg % 8 == 0, gx/gy pow2) ----
  const unsigned gx = gridDim.x, gy = gridDim.y;
  unsigned lin = blockIdx.x + gx * (blockIdx.y + gy * blockIdx.z);
  const unsigned nwg = gx * gy * gridDim.z;
  lin = (lin & 7u) * (nwg >> 3) + (lin >> 3);
  const unsigned bx = lin & (gx - 1u);
  const unsigned tmp = lin >> __builtin_ctz(gx);
  const unsigned by = tmp & (gy - 1u);
  const unsigned bz = tmp >> __builtin_ctz(gy);

  const int z = (int)bz;
  A += (size_t)z * bA;
  B += (size_t)z * bB;
  const size_t tileM = (size_t)by * 256;
  const size_t tileN = (size_t)bx * BN;

  // ---- staging bases (global pre-swizzled, LDS linear) ----
  const int sub = w & 3, half = w >> 2;
  const int rA = sub * 8 + half * 128 + (l >> 3);          // stripe q adds q*32
  const int cA = (l & 7) ^ (rA & 7) ^ ((rA >> 3) & 3);     // invariant in q
  const unsigned short* srcA0 = A + (tileM + rA) * (size_t)K + (cA << 3);
  const int ldsA0 = (sub * 8 + half * 128) * 64;

  const int rB = w * 8 + (l >> 3);                         // stripe j adds j*64
  const int cB = (l & 7) ^ (rB & 7) ^ ((rB >> 3) & 3);     // invariant in j
  const unsigned short* srcB0 = B + (tileN + rB) * (size_t)K + (cB << 3);
  const int ldsB0 = (w * 8) * 64;

  const int wm = half;             // wave M origin / 128
  const int wn = sub;              // wave N origin / (BN/4)
  const int NT = K >> 6;           // K-tiles (>=16 and even at all call sites)

  float* oF = outF + (size_t)z * bO;
  unsigned short* oB = outB + (size_t)z * bO;
  const float* rs = res + (size_t)z * bR;

  if constexpr (BN == 256) {
    // =================== m201-style 4-phase, 16x16x32 ===================
    const int rowi = l & 15;
    const int kgrp = l >> 4;                       // 0..3
    const int fb = (l & 7) ^ ((l >> 3) & 1);       // swizzle base per lane

    f32x4 acc[8][4] = {};

    // ---- prologue: tile0 in consumption order: B0..3 then A0..3 ----
#pragma unroll
    for (int j = 0; j < 4; ++j) STB(j, 0, 0);
    STA(0, 0, 0); STA(1, 0, 0); STA(2, 0, 0); STA(3, 0, 0);
    asm volatile("s_waitcnt vmcnt(3)" ::: "memory");   // B*4 + A0 landed
    __builtin_amdgcn_s_barrier();

    for (int t = 0; t < NT; ++t) {
      const int bf = t & 1;
      const int aB = bf * ABUF, bBo = bf * BBUF;
      const int oA = (bf ^ 1) * ABUF, oBf = (bf ^ 1) * BBUF;
      const bool last = (t == NT - 1);
      s8vec bfr[4][2];
      s8vec afr[2][2];

#pragma unroll
      for (int p = 0; p < 4; ++p) {
        // -- reads for this phase: A frags mf=2p,2p+1 (ph0 also all B) --
        if (p == 0) {
#pragma unroll
          for (int nf = 0; nf < 4; ++nf) {
            const int br = (wn * 64 + nf * 16 + rowi) * 64;
#pragma unroll
            for (int kk = 0; kk < 2; ++kk)
              bfr[nf][kk] = *(const s8vec*)&Bs[bBo + br +
                  ((((kk << 2) + kgrp) ^ fb ^ ((nf << 1) & 3)) << 3)];
          }
        }
#pragma unroll
        for (int i = 0; i < 2; ++i) {
          const int mf = 2 * p + i;
          const int ar = (wm * 128 + mf * 16 + rowi) * 64;
#pragma unroll
          for (int kk = 0; kk < 2; ++kk)
            afr[i][kk] = *(const s8vec*)&As[aB + ar +
                ((((kk << 2) + kgrp) ^ fb ^ ((mf << 1) & 3)) << 3)];
        }
        // -- stage 2 stripes of t+1 (other buf), consumption order --
        if (!last) {
          if (p == 0)      { STB(0, t + 1, oBf); STB(1, t + 1, oBf); }
          else if (p == 1) { STB(2, t + 1, oBf); STB(3, t + 1, oBf); }
          else if (p == 2) { STA(0, t + 1, oA);  STA(1, t + 1, oA);  }
          else             { STA(2, t + 1, oA);  STA(3, t + 1, oA);  }
        }
        if (p == 0) asm volatile("s_waitcnt lgkmcnt(8)" ::: "memory");
        SB0();
        __builtin_amdgcn_s_barrier();
        asm volatile("s_waitcnt lgkmcnt(0)" ::: "memory");
        SB0();
        __builtin_amdgcn_s_setprio(1);
#pragma unroll
        for (int kk = 0; kk < 2; ++kk)
#pragma unroll
          for (int i = 0; i < 2; ++i)
#pragma unroll
            for (int nf = 0; nf < 4; ++nf)
              acc[2 * p + i][nf] = __builtin_amdgcn_mfma_f32_16x16x32_bf16(
                  afr[i][kk], bfr[nf][kk], acc[2 * p + i][nf], 0, 0, 0);
        SB0();
        __builtin_amdgcn_s_setprio(0);
        // -- phase-end counted vmcnt (ledger in header comment) --
        if (!last) {
          if (p == 0)      asm volatile("s_waitcnt vmcnt(4)" ::: "memory");
          else if (p == 1) asm volatile("s_waitcnt vmcnt(5)" ::: "memory");
          else if (p == 2) asm volatile("s_waitcnt vmcnt(6)" ::: "memory");
          else             asm volatile("s_waitcnt vmcnt(3)" ::: "memory");
        } else {
          if (p == 0)      asm volatile("s_waitcnt vmcnt(2)" ::: "memory");
          else if (p == 1) asm volatile("s_waitcnt vmcnt(1)" ::: "memory");
          else             asm volatile("s_waitcnt vmcnt(0)" ::: "memory");
        }
        __builtin_amdgcn_s_barrier();
      }
    }

    // ---- epilogue: C/D col=l&15, row=(l>>4)*4+reg ----
    float bcol[4];
    if (EPI >= 2) {
#pragma unroll
      for (int nf = 0; nf < 4; ++nf) bcol[nf] = bias[tileN + wn * 64 + nf * 16 + rowi];
    }
#pragma unroll
    for (int mf = 0; mf < 8; ++mf) {
#pragma unroll
      for (int r = 0; r < 4; ++r) {
        const size_t row = tileM + wm * 128 + mf * 16 + kgrp * 4 + r;
        const size_t rb = row * (size_t)N;
#pragma unroll
        for (int nf = 0; nf < 4; ++nf) {
          const size_t col = tileN + wn * 64 + nf * 16 + rowi;
          const float v = acc[mf][nf][r];
          if (EPI == 0) {
            oB[rb + col] = f2bf(v * scale);
          } else if (EPI == 1) {
            oF[rb + col] = v + rs[rb + col];
          } else if (EPI == 2) {
            oB[rb + col] = f2bf(fast_gelu(v + bcol[nf]));
          } else {
            oF[rb + col] = v + bcol[nf] + rs[rb + col];
          }
        }
      }
    }
  } else {
    // =================== round-4 2-window schedule (unchanged) ===================
    const int fr = l & 31;
    const int fq = l >> 5;
    const int swz = (l & 7) ^ ((l >> 3) & 3);
    int pc[4];
#pragma unroll
    for (int s = 0; s < 4; ++s) pc[s] = ((((s << 1) + fq) ^ swz) << 3);
    const int aoff = (wm * 128 + fr) * 64;
    const int boff0 = (wn * 32 + fr) * 64;

    f32x16 acc[4] = {};

    // ---- prologue: t0 full (oldest 6), then t1 B (2) + A01 (2) ----
    STA(0, 0, 0); STA(1, 0, 0); STA(2, 0, 0); STA(3, 0, 0);
    STB(0, 0, 0); STB(1, 0, 0);
    STB(0, 1, BBUF); STB(1, 1, BBUF);
    STA(0, 1, ABUF); STA(1, 1, ABUF);
    asm volatile("s_waitcnt vmcnt(4)" ::: "memory");
    __builtin_amdgcn_s_barrier();

    auto tile = [&](int t, int bf) {
      const int aB = bf * ABUF, bBo = bf * BBUF, oaB = (bf ^ 1) * ABUF;
      const bool g1 = (t + 1 < NT), g2 = (t + 2 < NT);
      s8vec b[4], aA[2][4], aC[2][4];

      // -- WA: read B,q0,q1; read-ahead q2,q3; stage A23(t+1, other buf) --
#pragma unroll
      for (int s = 0; s < 4; ++s) {
        b[s]     = *(const s8vec*)&Bs[bBo + boff0 + pc[s]];
        aA[0][s] = *(const s8vec*)&As[aB + aoff + 0 * 2048 + pc[s]];
        aA[1][s] = *(const s8vec*)&As[aB + aoff + 1 * 2048 + pc[s]];
      }
      SB0();
#pragma unroll
      for (int s = 0; s < 4; ++s) {
        aC[0][s] = *(const s8vec*)&As[aB + aoff + 2 * 2048 + pc[s]];
        aC[1][s] = *(const s8vec*)&As[aB + aoff + 3 * 2048 + pc[s]];
      }
      if (g1) { STA(2, t + 1, oaB); STA(3, t + 1, oaB); }
      SB0();
      asm volatile("s_waitcnt lgkmcnt(8)" ::: "memory");
      SB0();
      __builtin_amdgcn_s_setprio(1);
#pragma unroll
      for (int s = 0; s < 4; ++s)
#pragma unroll
        for (int i = 0; i < 2; ++i)
          acc[i] = __builtin_amdgcn_mfma_f32_32x32x16_bf16(aA[i][s], b[s], acc[i], 0, 0, 0);
      SB0();
      __builtin_amdgcn_s_setprio(0);
      __builtin_amdgcn_s_barrier();

      // -- WB: stage B(t+2)+A01(t+2) (this buf); MFMA half2; boundary vmcnt --
      if (g2) {
        STB(0, t + 2, bBo); STB(1, t + 2, bBo);
        STA(0, t + 2, aB); STA(1, t + 2, aB);
      }
      SB0();
      asm volatile("s_waitcnt lgkmcnt(0)" ::: "memory");
      SB0();
      __builtin_amdgcn_s_setprio(1);
#pragma unroll
      for (int s = 0; s < 4; ++s)
#pragma unroll
        for (int i = 0; i < 2; ++i)
          acc[2 + i] = __builtin_amdgcn_mfma_f32_32x32x16_bf16(aC[i][s], b[s], acc[2 + i], 0, 0, 0);
      SB0();
      __builtin_amdgcn_s_setprio(0);
      if (g2) asm volatile("s_waitcnt vmcnt(4)" ::: "memory");
      else    asm volatile("s_waitcnt vmcnt(0)" ::: "memory");
      __builtin_amdgcn_s_barrier();
    };

    for (int t = 0; t < NT; t += 2) { tile(t, 0); tile(t + 1, 1); }

    // ---- epilogue: C/D col=lane&31, row=(reg&3)+8*(reg>>2)+4*(lane>>5) ----
    float bc;
    if (EPI >= 2) bc = bias[tileN + wn * 32 + fr];
#pragma unroll
    for (int mf = 0; mf < 4; ++mf) {
#pragma unroll
      for (int r = 0; r < 16; ++r) {
        const size_t row = tileM + wm * 128 + (mf << 5) + (r & 3) + ((r >> 2) << 3) + (fq << 2);
        const size_t rb = row * (size_t)N;
        const size_t col = tileN + wn * 32 + fr;
        const float v = acc[mf][r];
        if (EPI == 0) {
          oB[rb + col] = f2bf(v * scale);
        } else if (EPI == 1) {
          oF[rb + col] = v + rs[rb + col];
        } else if (EPI == 2) {
          oB[rb + col] = f2bf(fast_gelu(v + bc));
        } else {
          oF[rb + col] = v + bc + rs[rb + col];
        }
      }
    }
  }
}

// ---------- LayerNorm over rows of 1024 fp32 -> bf16 ----------
__global__ __launch_bounds__(256) void ln_row(
    const float* __restrict__ x, const float* __restrict__ gamma,
    const float* __restrict__ beta, unsigned short* __restrict__ out)
{
  const int row = blockIdx.x;
  const float4* xr = (const float4*)(x + (size_t)row * 1024);
  const int tid = threadIdx.x;
  float4 v = xr[tid];
  float s = v.x + v.y + v.z + v.w;
  float q = v.x * v.x + v.y * v.y + v.z * v.z + v.w * v.w;
#pragma unroll
  for (int off = 32; off > 0; off >>= 1) {
    s += __shfl_down(s, off);
    q += __shfl_down(q, off);
  }
  __shared__ float rs_[4], rq_[4];
  const int w = tid >> 6, l = tid & 63;
  if (l == 0) { rs_[w] = s; rq_[w] = q; }
  __syncthreads();
  s = rs_[0] + rs_[1] + rs_[2] + rs_[3];
  q = rq_[0] + rq_[1] + rq_[2] + rq_[3];
  const float mu = s * (1.0f / 1024.0f);
  const float var = q * (1.0f / 1024.0f) - mu * mu;
  const float rstd = rsqrtf(var + 1e-5f);
  const float4 g = ((const float4*)gamma)[tid];
  const float4 b = ((const float4*)beta)[tid];
  us4 o;
  o.x = f2bf((v.x - mu) * rstd * g.x + b.x);
  o.y = f2bf((v.y - mu) * rstd * g.y + b.y);
  o.z = f2bf((v.z - mu) * rstd * g.z + b.z);
  o.w = f2bf((v.w - mu) * rstd * g.w + b.w);
  ((us4*)(out + (size_t)row * 1024))[tid] = o;
}

// ---------- softmax over rows of 2048 bf16 -> bf16 ----------
__global__ __launch_bounds__(256) void softmax_row(
    const unsigned short* __restrict__ sc, unsigned short* __restrict__ pr)
{
  const int row = blockIdx.x;
  const s8vec* s8 = (const s8vec*)(sc + (size_t)row * 2048);
  const int tid = threadIdx.x;
  s8vec a = s8[tid];                 // 8 bf16
  float x[8];
#pragma unroll
  for (int i = 0; i < 8; ++i) x[i] = bf2f((unsigned short)a[i]);
  float mx = x[0];
#pragma unroll
  for (int i = 1; i < 8; ++i) mx = fmaxf(mx, x[i]);
#pragma unroll
  for (int off = 32; off > 0; off >>= 1) mx = fmaxf(mx, __shfl_down(mx, off));
  __shared__ float red[4];
  const int w = tid >> 6, l = tid & 63;
  if (l == 0) red[w] = mx;
  __syncthreads();
  mx = fmaxf(fmaxf(red[0], red[1]), fmaxf(red[2], red[3]));
  __syncthreads();
  float e[8], s = 0.f;
#pragma unroll
  for (int i = 0; i < 8; ++i) { e[i] = __expf(x[i] - mx); s += e[i]; }
#pragma unroll
  for (int off = 32; off > 0; off >>= 1) s += __shfl_down(s, off);
  if (l == 0) red[w] = s;
  __syncthreads();
  s = red[0] + red[1] + red[2] + red[3];
  const float inv = 1.0f / s;
  s8vec o;
#pragma unroll
  for (int i = 0; i < 8; ++i) o[i] = (short)f2bf(e[i] * inv);
  ((s8vec*)(pr + (size_t)row * 2048))[tid] = o;
}

// ---------- fast 64x64-tile transposes (vectorized; G13) ----------
// f32 in [R][C] -> bf16 out [C][R]
__global__ __launch_bounds__(256) void tconv_f32(
    const float* __restrict__ in, unsigned short* __restrict__ out, int R, int C)
{
  __shared__ float tile[64][65];
  const int tid = threadIdx.x;
  const int c0 = blockIdx.x * 64, r0 = blockIdx.y * 64;
#pragma unroll
  for (int k2 = 0; k2 < 4; ++k2) {
    const int idx = tid + k2 * 256;
    const int row = idx >> 4, c4 = (idx & 15) << 2;
    const float4 v = *(const float4*)&in[(size_t)(r0 + row) * C + c0 + c4];
    tile[row][c4] = v.x; tile[row][c4 + 1] = v.y;
    tile[row][c4 + 2] = v.z; tile[row][c4 + 3] = v.w;
  }
  __syncthreads();
#pragma unroll
  for (int k2 = 0; k2 < 4; ++k2) {
    const int idx = tid + k2 * 256;
    const int cc = idx >> 4, r4 = (idx & 15) << 2;
    us4 o;
#pragma unroll
    for (int j = 0; j < 4; ++j) o[j] = f2bf(tile[r4 + j][cc]);
    *(us4*)&out[(size_t)(c0 + cc) * R + r0 + r4] = o;
  }
}

// bf16 in [R][C] -> bf16 out [C][R], batched
__global__ __launch_bounds__(256) void tconv_bf16(
    const unsigned short* __restrict__ in, unsigned short* __restrict__ out,
    int R, int C, long long bIn, long long bOut)
{
  __shared__ unsigned short tile[64][66];
  const int tid = threadIdx.x;
  const int z = blockIdx.z;
  in += (size_t)z * bIn;
  out += (size_t)z * bOut;
  const int c0 = blockIdx.x * 64, r0 = blockIdx.y * 64;
#pragma unroll
  for (int k2 = 0; k2 < 2; ++k2) {
    const int idx = tid + k2 * 256;
    const int row = idx >> 3, c8 = (idx & 7) << 3;
    const us8 v = *(const us8*)&in[(size_t)(r0 + row) * C + c0 + c8];
#pragma unroll
    for (int j = 0; j < 8; ++j) tile[row][c8 + j] = v[j];
  }
  __syncthreads();
#pragma unroll
  for (int k2 = 0; k2 < 4; ++k2) {
    const int idx = tid + k2 * 256;
    const int cc = idx >> 4, r4 = (idx & 15) << 2;
    us4 o;
#pragma unroll
    for (int j = 0; j < 4; ++j) o[j] = tile[r4 + j][cc];
    *(us4*)&out[(size_t)(c0 + cc) * R + r0 + r4] = o;
  }
}

// ---------- launch ----------
extern "C" void kernel_launch(void* const* d_in, const int* in_sizes, int n_in,
                              void* d_out, int out_size, void* d_ws, size_t ws_size,
                              hipStream_t stream)
{
  (void)in_sizes; (void)n_in; (void)out_size; (void)ws_size;
  const float* src = (const float*)d_in[0];
  const float* g1  = (const float*)d_in[1];
  const float* be1 = (const float*)d_in[2];
  const float* g2  = (const float*)d_in[3];
  const float* be2 = (const float*)d_in[4];
  const float* w1  = (const float*)d_in[5];
  const float* b1  = (const float*)d_in[6];
  const float* w2  = (const float*)d_in[7];
  const float* b2  = (const float*)d_in[8];
  float* out = (float*)d_out;

  // workspace layout (bytes). Peak = 184,549,376.
  char* ws = (char*)d_ws;
  const size_t SZ_NORMX  = (size_t)8192 * 1024 * 2;     // 16 MiB
  const size_t SZ_SCORES = (size_t)4 * 2048 * 2048 * 4; // 64 MiB region (scores bf16 uses half; hbuf uses all)
  const size_t SZ_PROBS  = (size_t)4 * 2048 * 2048 * 2; // 32 MiB
  const size_t SZ_X      = (size_t)8192 * 1024 * 4;     // 32 MiB
  const size_t SZ_W1T    = (size_t)1024 * 4096 * 2;     // 8 MiB

  unsigned short* normx  = (unsigned short*)(ws);
  unsigned short* normxT = (unsigned short*)(ws + SZ_NORMX);
  unsigned short* scores = (unsigned short*)(ws + 2 * SZ_NORMX);
  unsigned short* probs  = (unsigned short*)(ws + 2 * SZ_NORMX + SZ_SCORES);
  float*          xbuf   = (float*)(ws + 2 * SZ_NORMX + SZ_SCORES + SZ_PROBS);
  unsigned short* w1t    = (unsigned short*)(ws + 2 * SZ_NORMX + SZ_SCORES + SZ_PROBS + SZ_X);
  unsigned short* w2t    = (unsigned short*)(ws + 2 * SZ_NORMX + SZ_SCORES + SZ_PROBS + SZ_X + SZ_W1T);
  unsigned short* normx2 = normx;                       // reuse (dead after attn)
  unsigned short* hbuf   = scores;                      // reuse (dead after softmax)

  // weights fp32 -> bf16 transposed (every call; ws is re-poisoned)
  tconv_f32<<<dim3(64, 16), 256, 0, stream>>>(w1, w1t, 1024, 4096);
  tconv_f32<<<dim3(16, 64), 256, 0, stream>>>(w2, w2t, 4096, 1024);

  // LN1
  ln_row<<<8192, 256, 0, stream>>>(src, g1, be1, normx);
  // normx^T per batch (for PV as NT)
  tconv_bf16<<<dim3(16, 32, 4), 256, 0, stream>>>(
      normx, normxT, 2048, 1024, (long long)2048 * 1024, (long long)1024 * 2048);

  // scores = bf16(normx . normx^T / 32)
  gemm_nt8<256, 0><<<dim3(8, 8, 4), 512, 0, stream>>>(
      normx, normx, nullptr, scores, nullptr, nullptr,
      2048, 2048, 1024,
      (long long)2048 * 1024, (long long)2048 * 1024, (long long)2048 * 2048, 0, 0.03125f);

  // softmax rows (bf16 in/out)
  softmax_row<<<8192, 256, 0, stream>>>(scores, probs);

  // x = probs . normx + src
  gemm_nt8<128, 1><<<dim3(8, 8, 4), 512, 0, stream>>>(
      probs, normxT, xbuf, nullptr, nullptr, src,
      2048, 1024, 2048,
      (long long)2048 * 2048, (long long)1024 * 2048, (long long)2048 * 1024,
      (long long)2048 * 1024, 1.0f);

  // LN2
  ln_row<<<8192, 256, 0, stream>>>(xbuf, g2, be2, normx2);

  // h = gelu(normx2 . w1 + b1)
  gemm_nt8<256, 2><<<dim3(16, 32, 1), 512, 0, stream>>>(
      normx2, w1t, nullptr, hbuf, b1, nullptr,
      8192, 4096, 1024, 0, 0, 0, 0, 1.0f);

  // out = h . w2 + b2 + x
  gemm_nt8<128, 3><<<dim3(8, 32, 1), 512, 0, stream>>>(
      hbuf, w2t, out, nullptr, b2, xbuf,
      8192, 1024, 4096, 0, 0, 0, 0, 1.0f);
}